// Round 1
// baseline (54.745 us; speedup 1.0000x reference)
//
#include <hip/hip_runtime.h>
#include <math.h>

#define EPS 1e-8f
constexpr int N = 8192;
constexpr int H = 256;
constexpr int ROWS_PER_BLOCK = 16;
constexpr int COLS_PER_BLOCK = 1024;   // 256 threads * float4

// ---------------------------------------------------------------------------
// Kernel 1: p1 = pattern1 @ Wp.T + bp ; p2 = pattern2 @ Wp.T + bp ; norms.
// ws[0:256)=p1, ws[256:512)=p2, ws[512]=||p1||, ws[513]=||p2||
// ---------------------------------------------------------------------------
__global__ __launch_bounds__(256) void prep_kernel(
    const float* __restrict__ pat1, const float* __restrict__ pat2,
    const float* __restrict__ Wp, const float* __restrict__ bp,
    float* __restrict__ ws) {
  const int h = threadIdx.x;  // 0..255
  const float w0 = Wp[h * 3 + 0], w1 = Wp[h * 3 + 1], w2 = Wp[h * 3 + 2];
  const float b = bp[h];
  const float v1 = fmaf(w0, pat1[0], fmaf(w1, pat1[1], fmaf(w2, pat1[2], b)));
  const float v2 = fmaf(w0, pat2[0], fmaf(w1, pat2[1], fmaf(w2, pat2[2], b)));
  ws[h] = v1;
  ws[256 + h] = v2;
  __shared__ float r1[256], r2[256];
  r1[h] = v1 * v1;
  r2[h] = v2 * v2;
  __syncthreads();
  for (int s = 128; s > 0; s >>= 1) {
    if (h < s) { r1[h] += r1[h + s]; r2[h] += r2[h + s]; }
    __syncthreads();
  }
  if (h == 0) {
    ws[512] = sqrtf(r1[0]);
    ws[513] = sqrtf(r2[0]);
  }
}

// ---------------------------------------------------------------------------
// Kernel 2: per row i of working_memory:
//   props_row[h] = wm[i]·Wq[h] + bq[h]  (h = 0..255)
//   m1[i] = sigmoid((props_row·p1) / max(||props_row||·||p1||, EPS)), same m2
//   also stash obj[i] = wm[i][2], subj[i] = wm[i][0]
// One wave (64 lanes) per row; each lane covers 4 h-values.
// ---------------------------------------------------------------------------
__global__ __launch_bounds__(256) void match_kernel(
    const float* __restrict__ wm, const float* __restrict__ Wq,
    const float* __restrict__ bq, const float* __restrict__ ws,
    float* __restrict__ m1, float* __restrict__ m2,
    float* __restrict__ obj, float* __restrict__ subj) {
  const int row = (blockIdx.x * blockDim.x + threadIdx.x) >> 6;
  const int lane = threadIdx.x & 63;
  if (row >= N) return;
  const float x0 = wm[row * 3 + 0];
  const float x1 = wm[row * 3 + 1];
  const float x2 = wm[row * 3 + 2];
  const float* __restrict__ p1 = ws;
  const float* __restrict__ p2 = ws + 256;
  float s0 = 0.f, s1 = 0.f, s2 = 0.f;
#pragma unroll
  for (int k = 0; k < 4; ++k) {
    const int h = lane + k * 64;
    const float v = fmaf(Wq[h * 3 + 0], x0,
                    fmaf(Wq[h * 3 + 1], x1,
                    fmaf(Wq[h * 3 + 2], x2, bq[h])));
    s0 = fmaf(v, v, s0);
    s1 = fmaf(v, p1[h], s1);
    s2 = fmaf(v, p2[h], s2);
  }
#pragma unroll
  for (int off = 32; off > 0; off >>= 1) {
    s0 += __shfl_xor(s0, off, 64);
    s1 += __shfl_xor(s1, off, 64);
    s2 += __shfl_xor(s2, off, 64);
  }
  if (lane == 0) {
    const float pn = sqrtf(s0);
    const float n1 = ws[512], n2 = ws[513];
    const float d1 = fmaxf(pn * n1, EPS);
    const float d2 = fmaxf(pn * n2, EPS);
    const float z1 = s1 / d1;
    const float z2 = s2 / d2;
    m1[row] = 1.f / (1.f + __expf(-z1));
    m2[row] = 1.f / (1.f + __expf(-z2));
    obj[row] = x2;
    subj[row] = x0;
  }
}

// ---------------------------------------------------------------------------
// Kernel 3: out[i][j] = m1[i]*m2[j]*sigmoid(t/max(|t|,EPS)), t = obj[i]*subj[j]
// diagonal zeroed. Common path: link = sigmoid(+/-1) constants (no exp).
// ---------------------------------------------------------------------------
__device__ __forceinline__ float elem(float a_m1, float oi, float b_m2,
                                      float sj, int i, int j) {
  const float t = oi * sj;
  const float at = fabsf(t);
  float link;
  if (__builtin_expect(at < EPS, 0)) {
    // exact reference path: sigmoid(t / EPS)
    link = 1.f / (1.f + __expf(-(t / EPS)));
  } else {
    link = (t > 0.f) ? 0.7310585786300049f : 0.2689414213699951f;
  }
  const float v = a_m1 * b_m2 * link;
  return (i == j) ? 0.f : v;
}

__global__ __launch_bounds__(256) void outer_kernel(
    const float* __restrict__ m1, const float* __restrict__ m2,
    const float* __restrict__ obj, const float* __restrict__ subj,
    float* __restrict__ out) {
  const int jBase = blockIdx.x * COLS_PER_BLOCK + threadIdx.x * 4;
  const int iBase = blockIdx.y * ROWS_PER_BLOCK;
  const float4 m2v = *reinterpret_cast<const float4*>(m2 + jBase);
  const float4 sjv = *reinterpret_cast<const float4*>(subj + jBase);
#pragma unroll
  for (int r = 0; r < ROWS_PER_BLOCK; ++r) {
    const int i = iBase + r;
    const float a = m1[i];
    const float oi = obj[i];
    float4 o;
    o.x = elem(a, oi, m2v.x, sjv.x, i, jBase + 0);
    o.y = elem(a, oi, m2v.y, sjv.y, i, jBase + 1);
    o.z = elem(a, oi, m2v.z, sjv.z, i, jBase + 2);
    o.w = elem(a, oi, m2v.w, sjv.w, i, jBase + 3);
    *reinterpret_cast<float4*>(out + (size_t)i * N + jBase) = o;
  }
}

// ---------------------------------------------------------------------------
extern "C" void kernel_launch(void* const* d_in, const int* in_sizes, int n_in,
                              void* d_out, int out_size, void* d_ws,
                              size_t ws_size, hipStream_t stream) {
  const float* pat1 = (const float*)d_in[0];
  const float* pat2 = (const float*)d_in[1];
  const float* wm   = (const float*)d_in[2];
  const float* Wp   = (const float*)d_in[3];
  const float* bp   = (const float*)d_in[4];
  const float* Wq   = (const float*)d_in[5];
  const float* bq   = (const float*)d_in[6];
  float* out = (float*)d_out;

  // ws layout (floats): [0,1024) p1/p2/norms ; then m1, m2, obj, subj (N each)
  float* ws   = (float*)d_ws;
  float* m1   = ws + 1024;
  float* m2   = m1 + N;
  float* obj  = m2 + N;
  float* subj = obj + N;

  prep_kernel<<<1, 256, 0, stream>>>(pat1, pat2, Wp, bp, ws);
  match_kernel<<<N / 4, 256, 0, stream>>>(wm, Wq, bq, ws, m1, m2, obj, subj);
  dim3 grid(N / COLS_PER_BLOCK, N / ROWS_PER_BLOCK);
  outer_kernel<<<grid, 256, 0, stream>>>(m1, m2, obj, subj, out);
}